// Round 11
// baseline (2129.894 us; speedup 1.0000x reference)
//
#include <hip/hip_runtime.h>
#include <hip/hip_bf16.h>

typedef unsigned short u16;
typedef unsigned int   u32;

#define BB   2
#define NN   2048
#define HS   16
#define DH   64
#define NM   16
#define JT   2064   // NM + NN
#define DIM  1024
#define CT   26     // j-tiles per chunk (416 keys)
#define JC   5      // ceil(129/26)

#define SPLITSZ ((size_t)BB * HS * JT * DH)   // elements per K-split plane

__device__ __forceinline__ float bfval(u16 u) { return __uint_as_float(((u32)u) << 16); }
__device__ __forceinline__ float lo16(u32 u)  { return __uint_as_float(u << 16); }
__device__ __forceinline__ float hi16(u32 u)  { return __uint_as_float(u & 0xffff0000u); }
__device__ __forceinline__ u16 f2bf(float f)
{
    __hip_bfloat16 h = __float2bfloat16(f);
    return *(u16*)&h;
}

typedef __bf16 bf16x8 __attribute__((ext_vector_type(8)));
typedef float  f32x4  __attribute__((ext_vector_type(4)));

// ---------------------------------------------------------------------------
// mem_k rows -> K-split planes (hi/mid/lo bf16) at key rows 0..15.
// ---------------------------------------------------------------------------
__global__ void prep_mem_kernel(const float* __restrict__ mem_k, u16* __restrict__ k_sp)
{
    int t = blockIdx.x * 256 + threadIdx.x;          // 0 .. 32767
    int d = t & 63, j = (t >> 6) & 15, h = (t >> 10) & 15, b = (t >> 14) & 1;
    float x = mem_k[(h * NM + j) * DH + d];
    size_t di = ((size_t)(b * HS + h) * JT + j) * DH + d;
    u16 sh = f2bf(x);
    float d1 = x - bfval(sh);
    u16 sm = f2bf(d1);
    u16 sl = f2bf(d1 - bfval(sm));
    k_sp[di] = sh; k_sp[di + SPLITSZ] = sm; k_sp[di + 2 * SPLITSZ] = sl;
}

// ---------------------------------------------------------------------------
// Wo f32 [k][n] -> WoT bf16 [n][k] (B-frag native layout for the epilogue).
// ---------------------------------------------------------------------------
__global__ void prep_wot_kernel(const float* __restrict__ Wo, u16* __restrict__ wot)
{
    int t = blockIdx.x * 256 + threadIdx.x;          // 0 .. 1048575
    int k = t & 1023, n = t >> 10;
    wot[(size_t)n * 1024 + k] = f2bf(Wo[(size_t)k * 1024 + n]);
}

// ---------------------------------------------------------------------------
// Exact-f32 GEMM via 6-pass bf16 split MFMA (core verified R7-R10).
// mode 0: bf16 scatter to [b][h][2048][64] head layout (V)
// mode 1: f32 row-major C = acc (Q -> d_out)
// mode 2: K: split into hi/mid/lo bf16 planes, scatter [b][h][NM+i][64]
// ---------------------------------------------------------------------------
__global__ __launch_bounds__(256) void gemm_kernel(
    const float* __restrict__ A, const float* __restrict__ Bw,
    u16* __restrict__ dst16, float* __restrict__ dstf, int mode)
{
    __shared__ __align__(16) u16 a_h[128][32];
    __shared__ __align__(16) u16 a_m[128][32];
    __shared__ __align__(16) u16 a_l[128][32];
    __shared__ __align__(16) u16 b_hT[64][32];
    __shared__ __align__(16) u16 b_mT[64][32];
    __shared__ __align__(16) u16 b_lT[64][32];

    const int tid  = threadIdx.x;
    const int m0   = blockIdx.x * 128;
    const int n0   = blockIdx.y * 64;
    const int wave = tid >> 6, lane = tid & 63;
    const int ln16 = lane & 15, quad = lane >> 4;

    const int arow = tid >> 1;            // 0..127
    const int ac   = (tid & 1) * 16;      // 0 or 16
    const int brow = tid >> 3;            // 0..31
    const int bc   = (tid & 7) * 8;       // 0..56

    f32x4 acc[8] = {};

    for (int k0 = 0; k0 < 1024; k0 += 32) {
        float av[16];
        {
            const float4* ap = (const float4*)&A[(size_t)(m0 + arow) * 1024 + k0 + ac];
            *(float4*)&av[0]  = ap[0]; *(float4*)&av[4]  = ap[1];
            *(float4*)&av[8]  = ap[2]; *(float4*)&av[12] = ap[3];
        }
        float bv[8];
        {
            const float4* bp = (const float4*)&Bw[(size_t)(k0 + brow) * 1024 + n0 + bc];
            *(float4*)&bv[0] = bp[0]; *(float4*)&bv[4] = bp[1];
        }
        u16 ah[16], am[16], al[16], bh[8], bm[8], bl[8];
        #pragma unroll
        for (int e = 0; e < 16; ++e) {
            ah[e] = f2bf(av[e]);
            float d1 = av[e] - bfval(ah[e]);
            am[e] = f2bf(d1);
            al[e] = f2bf(d1 - bfval(am[e]));
        }
        #pragma unroll
        for (int e = 0; e < 8; ++e) {
            bh[e] = f2bf(bv[e]);
            float d1 = bv[e] - bfval(bh[e]);
            bm[e] = f2bf(d1);
            bl[e] = f2bf(d1 - bfval(bm[e]));
        }
        __syncthreads();
        *(uint4*)&a_h[arow][ac]     = ((uint4*)ah)[0];
        *(uint4*)&a_h[arow][ac + 8] = ((uint4*)ah)[1];
        *(uint4*)&a_m[arow][ac]     = ((uint4*)am)[0];
        *(uint4*)&a_m[arow][ac + 8] = ((uint4*)am)[1];
        *(uint4*)&a_l[arow][ac]     = ((uint4*)al)[0];
        *(uint4*)&a_l[arow][ac + 8] = ((uint4*)al)[1];
        #pragma unroll
        for (int e = 0; e < 8; ++e) {
            b_hT[bc + e][brow] = bh[e];
            b_mT[bc + e][brow] = bm[e];
            b_lT[bc + e][brow] = bl[e];
        }
        __syncthreads();

        bf16x8 a0h = *(const bf16x8*)&a_h[wave * 32 + ln16][quad * 8];
        bf16x8 a0m = *(const bf16x8*)&a_m[wave * 32 + ln16][quad * 8];
        bf16x8 a0l = *(const bf16x8*)&a_l[wave * 32 + ln16][quad * 8];
        bf16x8 a1h = *(const bf16x8*)&a_h[wave * 32 + 16 + ln16][quad * 8];
        bf16x8 a1m = *(const bf16x8*)&a_m[wave * 32 + 16 + ln16][quad * 8];
        bf16x8 a1l = *(const bf16x8*)&a_l[wave * 32 + 16 + ln16][quad * 8];
        #pragma unroll
        for (int c = 0; c < 4; ++c) {
            bf16x8 bh_ = *(const bf16x8*)&b_hT[c * 16 + ln16][quad * 8];
            bf16x8 bm_ = *(const bf16x8*)&b_mT[c * 16 + ln16][quad * 8];
            bf16x8 bl_ = *(const bf16x8*)&b_lT[c * 16 + ln16][quad * 8];
            acc[c]     = __builtin_amdgcn_mfma_f32_16x16x32_bf16(a0m, bm_, acc[c],     0, 0, 0);
            acc[c]     = __builtin_amdgcn_mfma_f32_16x16x32_bf16(a0h, bl_, acc[c],     0, 0, 0);
            acc[c]     = __builtin_amdgcn_mfma_f32_16x16x32_bf16(a0l, bh_, acc[c],     0, 0, 0);
            acc[c]     = __builtin_amdgcn_mfma_f32_16x16x32_bf16(a0h, bm_, acc[c],     0, 0, 0);
            acc[c]     = __builtin_amdgcn_mfma_f32_16x16x32_bf16(a0m, bh_, acc[c],     0, 0, 0);
            acc[c]     = __builtin_amdgcn_mfma_f32_16x16x32_bf16(a0h, bh_, acc[c],     0, 0, 0);
            acc[4 + c] = __builtin_amdgcn_mfma_f32_16x16x32_bf16(a1m, bm_, acc[4 + c], 0, 0, 0);
            acc[4 + c] = __builtin_amdgcn_mfma_f32_16x16x32_bf16(a1h, bl_, acc[4 + c], 0, 0, 0);
            acc[4 + c] = __builtin_amdgcn_mfma_f32_16x16x32_bf16(a1l, bh_, acc[4 + c], 0, 0, 0);
            acc[4 + c] = __builtin_amdgcn_mfma_f32_16x16x32_bf16(a1h, bm_, acc[4 + c], 0, 0, 0);
            acc[4 + c] = __builtin_amdgcn_mfma_f32_16x16x32_bf16(a1m, bh_, acc[4 + c], 0, 0, 0);
            acc[4 + c] = __builtin_amdgcn_mfma_f32_16x16x32_bf16(a1h, bh_, acc[4 + c], 0, 0, 0);
        }
    }

    #pragma unroll
    for (int hf = 0; hf < 2; ++hf) {
        #pragma unroll
        for (int c = 0; c < 4; ++c) {
            #pragma unroll
            for (int r = 0; r < 4; ++r) {
                int row = m0 + wave * 32 + hf * 16 + quad * 4 + r;
                int col = n0 + c * 16 + ln16;
                float v = acc[hf * 4 + c][r];
                if (mode == 1) {
                    dstf[(size_t)row * 1024 + col] = v;
                } else {
                    int b = row >> 11, i = row & 2047;
                    int hd = col >> 6, d = col & 63;
                    if (mode == 0) {
                        dst16[(((size_t)(b * HS + hd)) * NN + i) * DH + d] = f2bf(v);
                    } else {
                        size_t di = (((size_t)(b * HS + hd)) * JT + NM + i) * DH + d;
                        u16 sh = f2bf(v);
                        float d1 = v - bfval(sh);
                        u16 sm = f2bf(d1);
                        u16 sl = f2bf(d1 - bfval(sm));
                        dst16[di] = sh;
                        dst16[di + SPLITSZ] = sm;
                        dst16[di + 2 * SPLITSZ] = sl;
                    }
                }
            }
        }
    }
}

// ---------------------------------------------------------------------------
// Phase 1 (MFMA) v3: scores + partial top-8 per j-chunk.
// Per tile: [MFMA S -> LDS] bar [row-mapped mix from S b128 reads -> MX regs
// -> scan regs] bar. MX never touches LDS; pp read 16x/tile (broadcast).
// Thread (kk_r=tid&15, ti_r=tid>>4) owns mixed-head row (kk_r, i0+ti_r);
// identical summation order per (kk,cell) as R10 -> bit-identical scores.
// ---------------------------------------------------------------------------
#define SROW 260   // S row stride in floats (16B-aligned, bank-spread)

__global__ __launch_bounds__(256, 3) void score_topk_kernel(
    const u16* __restrict__ k_sp, const float* __restrict__ q_all,
    const float* __restrict__ pre,
    float* __restrict__ ws_val, u16* __restrict__ ws_idx)
{
    const int jc = blockIdx.x;
    const int iy = blockIdx.y;
    const int b  = blockIdx.z;
    const int ntiles = iy + 2;
    const int jt_lo = jc * CT;
    if (jt_lo >= ntiles) return;                 // block-uniform early exit
    const int jt_hi = min(jt_lo + CT, ntiles);

    __shared__ __align__(16) float S[16 * SROW]; // S[h][cell], cell = ti*16+tj
    __shared__ float pp[256];                    // pre_proj * 0.125

    const int tid  = threadIdx.x;
    const int i0   = iy * 16;
    const int wave = tid >> 6, lane = tid & 63;
    const int ln16 = lane & 15, quad = lane >> 4;

    pp[tid] = pre[tid] * 0.125f;

    // Q A-frags: 4 heads/wave x 2 K-halves x 3 splits, loaded once per block.
    bf16x8 qh[4][2], qm[4][2], ql[4][2];
    {
        const float* qrow = q_all + (size_t)(b * NN + i0 + ln16) * DIM;
        #pragma unroll
        for (int h4 = 0; h4 < 4; ++h4) {
            const int h = wave * 4 + h4;
            #pragma unroll
            for (int half = 0; half < 2; ++half) {
                const float* src = qrow + h * 64 + half * 32 + quad * 8;
                float4 u0 = *(const float4*)src;
                float4 u1 = *(const float4*)(src + 4);
                float xv[8] = {u0.x, u0.y, u0.z, u0.w, u1.x, u1.y, u1.z, u1.w};
                u16 eh[8], em[8], el[8];
                #pragma unroll
                for (int e = 0; e < 8; ++e) {
                    eh[e] = f2bf(xv[e]);
                    float d1 = xv[e] - bfval(eh[e]);
                    em[e] = f2bf(d1);
                    el[e] = f2bf(d1 - bfval(em[e]));
                }
                qh[h4][half] = *(bf16x8*)eh;
                qm[h4][half] = *(bf16x8*)em;
                ql[h4][half] = *(bf16x8*)el;
            }
        }
    }

    const int kk_r = tid & 15, ti_r = tid >> 4;   // row (kk_r, i0+ti_r)
    float tv[8];
    int   tx[8];
    #pragma unroll
    for (int t = 0; t < 8; ++t) { tv[t] = -1e30f; tx[t] = 0; }
    const int jlim = NM + i0 + ti_r;
    __syncthreads();                              // pp visible

    for (int jt = jt_lo; jt < jt_hi; ++jt) {
        // ---- MFMA S phase: wave w computes heads 4w..4w+3 ----
        #pragma unroll
        for (int h4 = 0; h4 < 4; ++h4) {
            const int h = wave * 4 + h4;
            const u16* kb = k_sp + ((size_t)(b * HS + h) * JT + jt * 16 + ln16) * DH;
            f32x4 acc = {};
            #pragma unroll
            for (int half = 0; half < 2; ++half) {
                const u16* k0 = kb + half * 32 + quad * 8;
                bf16x8 kh_ = *(const bf16x8*)(k0);
                bf16x8 km_ = *(const bf16x8*)(k0 + SPLITSZ);
                bf16x8 kl_ = *(const bf16x8*)(k0 + 2 * SPLITSZ);
                acc = __builtin_amdgcn_mfma_f32_16x16x32_bf16(qm[h4][half], km_, acc, 0, 0, 0);
                acc = __builtin_amdgcn_mfma_f32_16x16x32_bf16(qh[h4][half], kl_, acc, 0, 0, 0);
                acc = __builtin_amdgcn_mfma_f32_16x16x32_bf16(ql[h4][half], kh_, acc, 0, 0, 0);
                acc = __builtin_amdgcn_mfma_f32_16x16x32_bf16(qh[h4][half], km_, acc, 0, 0, 0);
                acc = __builtin_amdgcn_mfma_f32_16x16x32_bf16(qm[h4][half], kh_, acc, 0, 0, 0);
                acc = __builtin_amdgcn_mfma_f32_16x16x32_bf16(qh[h4][half], kh_, acc, 0, 0, 0);
            }
            #pragma unroll
            for (int r = 0; r < 4; ++r)
                S[h * SROW + (quad * 4 + r) * 16 + ln16] = acc[r];
        }
        __syncthreads();   // S ready

        // ---- mix into 16 registers (row kk_r, cells ti_r*16+0..15) ----
        float mx[16];
        #pragma unroll
        for (int t = 0; t < 16; ++t) mx[t] = 0.f;
        #pragma unroll
        for (int h = 0; h < 16; ++h) {
            const float4* sp = (const float4*)&S[h * SROW + ti_r * 16];
            float4 s0 = sp[0], s1 = sp[1], s2 = sp[2], s3 = sp[3];
            float p = pp[h * 16 + kk_r];
            mx[0]  += p * s0.x; mx[1]  += p * s0.y; mx[2]  += p * s0.z; mx[3]  += p * s0.w;
            mx[4]  += p * s1.x; mx[5]  += p * s1.y; mx[6]  += p * s1.z; mx[7]  += p * s1.w;
            mx[8]  += p * s2.x; mx[9]  += p * s2.y; mx[10] += p * s2.z; mx[11] += p * s2.w;
            mx[12] += p * s3.x; mx[13] += p * s3.y; mx[14] += p * s3.z; mx[15] += p * s3.w;
        }

        // ---- scan register MX (same j order / compares as R10) ----
        #pragma unroll
        for (int t2 = 0; t2 < 16; ++t2) {
            int j = jt * 16 + t2;
            if (j <= jlim) {
                float c = mx[t2];
                if (c > tv[7]) {
                    #pragma unroll
                    for (int t = 7; t >= 1; --t) {
                        if (c > tv[t - 1])      { tv[t] = tv[t - 1]; tx[t] = tx[t - 1]; }
                        else if (c > tv[t])     { tv[t] = c;         tx[t] = j; }
                    }
                    if (c > tv[0]) { tv[0] = c; tx[0] = j; }
                }
            }
        }
        __syncthreads();   // mix reads done before next tile's S writes
    }

    size_t base = ((((size_t)b * HS + kk_r) * NN + i0 + ti_r) * JC + jc) * 8;
    #pragma unroll
    for (int t = 0; t < 8; ++t) {
        ws_val[base + t] = tv[t];
        ws_idx[base + t] = (u16)tx[t];
    }
}

// ---------------------------------------------------------------------------
// Phase 2: merge partial top-8s -> softmax -> sparse PV (bf16 V ws, f32 mem_v)
// -> fused out-proj with pre-transposed bf16 WoT. (verbatim R10, verified)
// ---------------------------------------------------------------------------
__global__ __launch_bounds__(256) void merge_pv_kernel(
    const u16* __restrict__ v_bf, const float* __restrict__ mem_v,
    const float* __restrict__ ws_val, const u16* __restrict__ ws_idx,
    const float* __restrict__ post, const u16* __restrict__ wot,
    const float* __restrict__ bo, float* __restrict__ out)
{
    __shared__ __align__(16) float fsm[13312];
    float* dotsm = fsm + 8704;     // [4096]: w park [0..2047], j park [2048..4095]
    float* pp2   = fsm + 13056;    // [256] post_proj
    u16*   arows = (u16*)fsm;      // [16][1032] bf16 (PV rows)

    const int tid = threadIdx.x;
    const int b   = blockIdx.y;
    const int i0  = blockIdx.x * 16;
    const int ntiles = blockIdx.x + 2;
    const int jc_cnt = (ntiles + CT - 1) / CT;

    pp2[tid] = post[tid];

    const int kk_r = tid & 15, ti_r = tid >> 4;

    float tv[8];
    int   tx[8];
    #pragma unroll
    for (int t = 0; t < 8; ++t) { tv[t] = -1e30f; tx[t] = 0; }

    size_t rbase = (((size_t)b * HS + kk_r) * NN + i0 + ti_r) * JC;
    for (int jc = 0; jc < jc_cnt; ++jc) {
        #pragma unroll
        for (int t2 = 0; t2 < 8; ++t2) {
            float c = ws_val[(rbase + jc) * 8 + t2];
            int   j = ws_idx[(rbase + jc) * 8 + t2];
            if (c > tv[7]) {
                #pragma unroll
                for (int t = 7; t >= 1; --t) {
                    if (c > tv[t - 1])      { tv[t] = tv[t - 1]; tx[t] = tx[t - 1]; }
                    else if (c > tv[t])     { tv[t] = c;         tx[t] = j; }
                }
                if (c > tv[0]) { tv[0] = c; tx[0] = j; }
            }
        }
    }

    float m = tv[0];
    float wv[8], wsum = 0.f;
    #pragma unroll
    for (int t = 0; t < 8; ++t) { wv[t] = __expf(tv[t] - m); wsum += wv[t]; }
    float inv = 1.f / wsum;

    #pragma unroll
    for (int t = 0; t < 8; ++t) {
        dotsm[(kk_r * 16 + ti_r) * 8 + t]        = wv[t] * inv;
        dotsm[2048 + (kk_r * 16 + ti_r) * 8 + t] = __int_as_float(tx[t]);
    }
    __syncthreads();

    // PV: thread = (ti_o, k2)
    const int ti_o = tid >> 4, k2 = tid & 15;
    {
        float acc[64];
        #pragma unroll
        for (int d = 0; d < 64; ++d) acc[d] = 0.f;
        const u16*   vws_base  = v_bf  + (size_t)(b * HS + k2) * NN * DH;
        const float* vmem_base = mem_v + (size_t)k2 * NM * DH;

        for (int kk = 0; kk < 16; ++kk) {
            float p2 = pp2[kk * 16 + k2];
            for (int t = 0; t < 8; ++t) {
                float w = dotsm[(kk * 16 + ti_o) * 8 + t] * p2;
                int j = __float_as_int(dotsm[2048 + (kk * 16 + ti_o) * 8 + t]);
                if (j < NM) {
                    const float* vr = vmem_base + (size_t)j * DH;
                    #pragma unroll
                    for (int r = 0; r < 16; ++r) {
                        float4 u = *(const float4*)&vr[r * 4];
                        acc[r * 4 + 0] += w * u.x; acc[r * 4 + 1] += w * u.y;
                        acc[r * 4 + 2] += w * u.z; acc[r * 4 + 3] += w * u.w;
                    }
                } else {
                    const uint4* vr = (const uint4*)(vws_base + (size_t)(j - NM) * DH);
                    #pragma unroll
                    for (int r = 0; r < 8; ++r) {
                        uint4 u = vr[r];
                        acc[r * 8 + 0] += w * lo16(u.x); acc[r * 8 + 1] += w * hi16(u.x);
                        acc[r * 8 + 2] += w * lo16(u.y); acc[r * 8 + 3] += w * hi16(u.y);
                        acc[r * 8 + 4] += w * lo16(u.z); acc[r * 8 + 5] += w * hi16(u.z);
                        acc[r * 8 + 6] += w * lo16(u.w); acc[r * 8 + 7] += w * hi16(u.w);
                    }
                }
            }
        }
        #pragma unroll
        for (int d = 0; d < 64; ++d) {
            float o = acc[d];
            o = (o == o) ? o : 1e4f;             // V-side NaN sentinel (diagnostic)
            arows[ti_o * 1032 + k2 * 64 + d] = f2bf(o);
        }
    }
    __syncthreads();

    // fused out-projection: out_rows(16x1024) = arows(16x1024) @ Wo + bo
    const int wave = tid >> 6, lane = tid & 63;
    const int ln16 = lane & 15, quad = lane >> 4;

    f32x4 oacc[16];
    #pragma unroll
    for (int t = 0; t < 16; ++t) {
        float bv = bo[(t * 4 + wave) * 16 + ln16];
        oacc[t][0] = bv; oacc[t][1] = bv; oacc[t][2] = bv; oacc[t][3] = bv;
    }

    for (int k0 = 0; k0 < 1024; k0 += 32) {
        bf16x8 af = *(const bf16x8*)&arows[ln16 * 1032 + k0 + quad * 8];
        #pragma unroll
        for (int t = 0; t < 16; ++t) {
            const int n = (t * 4 + wave) * 16 + ln16;
            bf16x8 bf_ = *(const bf16x8*)&wot[(size_t)n * 1024 + k0 + quad * 8];
            oacc[t] = __builtin_amdgcn_mfma_f32_16x16x32_bf16(af, bf_, oacc[t], 0, 0, 0);
        }
    }

    #pragma unroll
    for (int t = 0; t < 16; ++t) {
        const int n = (t * 4 + wave) * 16 + ln16;
        #pragma unroll
        for (int r = 0; r < 4; ++r) {
            int row = quad * 4 + r;
            out[(size_t)(b * NN + i0 + row) * DIM + n] = oacc[t][r];
        }
    }
}

// ---------------------------------------------------------------------------
extern "C" void kernel_launch(void* const* d_in, const int* in_sizes, int n_in,
                              void* d_out, int out_size, void* d_ws, size_t ws_size,
                              hipStream_t stream)
{
    (void)in_sizes; (void)n_in; (void)out_size; (void)ws_size;
    const float* x     = (const float*)d_in[0];
    const float* Wq    = (const float*)d_in[1];
    const float* Wk    = (const float*)d_in[2];
    const float* Wv    = (const float*)d_in[3];
    const float* pre   = (const float*)d_in[4];
    const float* post  = (const float*)d_in[5];
    const float* mem_k = (const float*)d_in[6];
    const float* mem_v = (const float*)d_in[7];
    const float* Wo    = (const float*)d_in[8];
    const float* bo    = (const float*)d_in[9];

    // workspace (51.6 MB total, < 54.6 proven):
    //   K splits 3x bf16 [2][16][2064][64]            = 25.36 MB
    //   V bf16 [2][16][2048][64]                      =  8.39 MB
    //   partial top-8 val f32 [2][16][2048][JC=5][8]  = 10.49 MB
    //   partial top-8 idx u16                          =  5.24 MB
    //   WoT bf16 [1024][1024]                         =  2.10 MB
    u16*   k_sp   = (u16*)d_ws;
    u16*   v_bf   = k_sp + 3 * SPLITSZ;
    float* ws_val = (float*)(v_bf + (size_t)BB * HS * NN * DH);
    u16*   ws_idx = (u16*)(ws_val + (size_t)BB * HS * NN * JC * 8);
    u16*   wot    = ws_idx + (size_t)BB * HS * NN * JC * 8;
    float* q_tmp  = (float*)d_out;                           // Q f32 [b*n][1024]

    prep_mem_kernel<<<128, 256, 0, stream>>>(mem_k, k_sp);
    prep_wot_kernel<<<4096, 256, 0, stream>>>(Wo, wot);

    dim3 gg(32, 16);
    gemm_kernel<<<gg, 256, 0, stream>>>(x, Wq, nullptr, q_tmp, 1);  // Q -> d_out
    gemm_kernel<<<gg, 256, 0, stream>>>(x, Wk, k_sp, nullptr, 2);   // K -> split planes
    gemm_kernel<<<gg, 256, 0, stream>>>(x, Wv, v_bf, nullptr, 0);   // V -> bf16 ws

    dim3 gs(JC, 128, 2);
    score_topk_kernel<<<gs, 256, 0, stream>>>(k_sp, (const float*)d_out,
                                              pre, ws_val, ws_idx);

    dim3 ga(128, 2);
    merge_pv_kernel<<<ga, 256, 0, stream>>>(v_bf, mem_v, ws_val, ws_idx,
                                            post, wot, bo, (float*)d_out);
}